// Round 3
// baseline (188.396 us; speedup 1.0000x reference)
//
#include <hip/hip_runtime.h>
#include <hip/hip_bf16.h>
#include <math.h>

#define B_  2
#define T_  2048
#define C_  1024
#define H_  16
#define HD_ 64

typedef __attribute__((ext_vector_type(8))) short short8;
typedef __attribute__((ext_vector_type(4))) float floatx4;

__device__ __forceinline__ short f2bf(float f) {
    __hip_bfloat16 h = __float2bfloat16(f);
    return *reinterpret_cast<short*>(&h);
}

// fast 2^x (v_exp_f32 IS exp2)
__device__ __forceinline__ float fexp2(float x) {
#if __has_builtin(__builtin_amdgcn_exp2f)
    return __builtin_amdgcn_exp2f(x);
#else
    return exp2f(x);
#endif
}

// pack two fp32 -> two bf16 (truncating) in ONE v_perm_b32
__device__ __forceinline__ unsigned pack2bf(float a, float b) {
    return __builtin_amdgcn_perm(__float_as_uint(b), __float_as_uint(a),
                                 0x07060302u);
}

__device__ __forceinline__ void gld16(const void* g, void* l) {
    __builtin_amdgcn_global_load_lds(
        (const __attribute__((address_space(1))) void*)g,
        (__attribute__((address_space(3))) void*)l, 16, 0, 0);
}

// ---------------------------------------------------------------------------
// Cast x, qkv_w, out_w to bf16 (one shot, memory-bound).
// R14 lesson: the standalone cast is CHEAPER than fusing conversion into the
// GEMMs (fused fp32 staging re-reads operands in fp32 per block: FETCH x2.3).
// ---------------------------------------------------------------------------
__global__ __launch_bounds__(256)
void cast3(const float* __restrict__ x, const float* __restrict__ w1,
           const float* __restrict__ w2, short* __restrict__ xo,
           short* __restrict__ w1o, short* __restrict__ w2o)
{
    int gid = blockIdx.x * 256 + threadIdx.x;       // 1,048,576 threads x 8 elems
    const float* s; short* d; int off;
    if (gid < 524288)      { s = x;  d = xo;  off = gid; }
    else if (gid < 917504) { s = w1; d = w1o; off = gid - 524288; }
    else                   { s = w2; d = w2o; off = gid - 917504; }
    float4 a = ((const float4*)s)[(size_t)off * 2];
    float4 b = ((const float4*)s)[(size_t)off * 2 + 1];
    short8 v;
    v[0] = f2bf(a.x); v[1] = f2bf(a.y); v[2] = f2bf(a.z); v[3] = f2bf(a.w);
    v[4] = f2bf(b.x); v[5] = f2bf(b.y); v[6] = f2bf(b.z); v[7] = f2bf(b.w);
    *(short8*)(d + (size_t)off * 8) = v;
}

// ---------------------------------------------------------------------------
// bf16 MFMA GEMM (NT): out = A @ W^T + bias.  A:[M,K] bf16, W:[N,K] bf16.
// BM x BN x BK tile, 256 threads (4 waves 2x2). nk = K/BK steps; BK=64 sweet
// spot (R7-R12). Double-buffered LDS, one __syncthreads per step, distance-1
// prefetch; XOR chunk swizzle.
// MODE 0: fp32 out[m*N+n] + bias
// MODE 1: QKV scatter -> qb [B,H,T,HD] (x0.125*log2e), kb, vt [B,H,HD,T]
// ---------------------------------------------------------------------------
template<int MODE, int BM, int BN, int BK>
__global__ __launch_bounds__(256, 4)
void gemm_bf16(const short* __restrict__ A, const short* __restrict__ W,
               const float* __restrict__ bias, float* __restrict__ out,
               short* __restrict__ qb, short* __restrict__ kb,
               short* __restrict__ vt, int M, int N, int K)
{
    constexpr int MI  = BM / 32;
    constexpr int NJ  = BN / 32;
    constexpr int KS  = BK / 32;
    constexpr int CPR = BK / 8;
    constexpr int LC  = (CPR == 8) ? 3 : 4;
    constexpr int RPT = 256 / CPR;
    __shared__ __align__(16) short As[2][BM * BK];
    __shared__ __align__(16) short Bs[2][BN * BK];

    const int tid  = threadIdx.x;
    const int lane = tid & 63;
    const int w    = tid >> 6;
    const int m    = lane & 15, quad = lane >> 4;
    const int wrow = w >> 1, wcol = w & 1;
    const int nb = blockIdx.x, mb = blockIdx.y;

    const int g = (tid & (CPR - 1)) ^ ((tid >> LC) & (CPR - 1));
    const short* Ag = A + (size_t)(mb * BM + (tid >> LC)) * K + g * 8;
    const short* Wg = W + (size_t)(nb * BN + (tid >> LC)) * K + g * 8;

    int aoff[MI][KS], boff[NJ][KS];
#pragma unroll
    for (int i = 0; i < MI; i++) {
        int ar = wrow * (BM / 2) + i * 16 + m;
#pragma unroll
        for (int ks = 0; ks < KS; ks++)
            aoff[i][ks] = ar * BK + (((ks * 4 + quad) ^ (ar & (CPR - 1))) * 8);
    }
#pragma unroll
    for (int j = 0; j < NJ; j++) {
        int bc = wcol * (BN / 2) + j * 16 + m;
#pragma unroll
        for (int ks = 0; ks < KS; ks++)
            boff[j][ks] = bc * BK + (((ks * 4 + quad) ^ (bc & (CPR - 1))) * 8);
    }

    floatx4 acc[MI][NJ];
#pragma unroll
    for (int i = 0; i < MI; i++)
#pragma unroll
        for (int j = 0; j < NJ; j++) acc[i][j] = (floatx4){0.f, 0.f, 0.f, 0.f};

    auto stage = [&](int k0, int bi) {
#pragma unroll
        for (int i = 0; i < BM / RPT; i++)
            gld16(Ag + (size_t)(i * RPT) * K + k0, As[bi] + i * 2048 + tid * 8);
#pragma unroll
        for (int i = 0; i < BN / RPT; i++)
            gld16(Wg + (size_t)(i * RPT) * K + k0, Bs[bi] + i * 2048 + tid * 8);
    };

    const int nk = K / BK;
    stage(0, 0);
    __syncthreads();

    for (int ki = 0; ki < nk; ki++) {
        const int cur = ki & 1;
        if (ki + 1 < nk) stage((ki + 1) * BK, cur ^ 1);

        const short* Ac = &As[cur][0];
        const short* Bc = &Bs[cur][0];
        short8 af[MI][KS], bfr[NJ][KS];
#pragma unroll
        for (int i = 0; i < MI; i++)
#pragma unroll
            for (int ks = 0; ks < KS; ks++)
                af[i][ks] = *(const short8*)(Ac + aoff[i][ks]);
#pragma unroll
        for (int j = 0; j < NJ; j++)
#pragma unroll
            for (int ks = 0; ks < KS; ks++)
                bfr[j][ks] = *(const short8*)(Bc + boff[j][ks]);
#pragma unroll
        for (int i = 0; i < MI; i++)
#pragma unroll
            for (int j = 0; j < NJ; j++)
#pragma unroll
                for (int ks = 0; ks < KS; ks++)
                    acc[i][j] = __builtin_amdgcn_mfma_f32_16x16x32_bf16(
                        af[i][ks], bfr[j][ks], acc[i][j], 0, 0, 0);
        __syncthreads();
    }

    // C/D layout: col(n) = lane&15, row(m) = quad*4 + reg  [m89/m91 verified]
    const int row0 = mb * BM + wrow * (BM / 2);
    const int col0 = nb * BN + wcol * (BN / 2);

    if (MODE == 0) {
#pragma unroll
        for (int j = 0; j < NJ; j++) {
            int n = col0 + j * 16 + m;
            float bn = bias[n];
#pragma unroll
            for (int i = 0; i < MI; i++) {
#pragma unroll
                for (int r = 0; r < 4; r++) {
                    int mm = row0 + i * 16 + quad * 4 + r;
                    out[(size_t)mm * N + n] = acc[i][j][r] + bn;
                }
            }
        }
    } else {
        const int sec = col0 >> 10;               // 0=q 1=k 2=v
        const int h   = (col0 >> 6) & 15;
        if (sec <= 1) {
            short* dst = sec ? kb : qb;
            // q scale folds 1/sqrt(64) AND log2(e): softmax runs in exp2 domain
            const float sc = sec ? 1.0f : 0.18033688011112042f;
#pragma unroll
            for (int j = 0; j < NJ; j++) {
                int n = col0 + j * 16 + m;
                int d = n & 63;
                float bn = bias[n];
#pragma unroll
                for (int i = 0; i < MI; i++) {
                    int t0 = row0 + i * 16 + quad * 4;
                    int b  = t0 >> 11;
                    int t  = t0 & (T_ - 1);
#pragma unroll
                    for (int r = 0; r < 4; r++)
                        dst[((size_t)(b * H_ + h) * T_ + t + r) * HD_ + d] =
                            f2bf((acc[i][j][r] + bn) * sc);
                }
            }
        } else {
#pragma unroll
            for (int j = 0; j < NJ; j++) {
                int n = col0 + j * 16 + m;
                int d = n & 63;
                float bn = bias[n];
#pragma unroll
                for (int i = 0; i < MI; i++) {
                    int t0 = row0 + i * 16 + quad * 4;
                    int b  = t0 >> 11;
                    int t  = t0 & (T_ - 1);
                    ushort4 u;
                    u.x = (unsigned short)f2bf(acc[i][j][0] + bn);
                    u.y = (unsigned short)f2bf(acc[i][j][1] + bn);
                    u.z = (unsigned short)f2bf(acc[i][j][2] + bn);
                    u.w = (unsigned short)f2bf(acc[i][j][3] + bn);
                    *(ushort4*)(vt + ((size_t)(b * H_ + h) * HD_ + d) * T_ + t) = u;
                }
            }
        }
    }
}

// ---------------------------------------------------------------------------
// bf16 MFMA causal flash attention v5 — R17: v4 + LPT (descending-qt) map.
// R16 counters: Occupancy 11.7% (= 3.7 waves/CU avg), MfmaUtil 15%, VALU 23%,
// HBM 3.6% -> latency-bound from pair-tail imbalance: the snake map's small
// partner (2qs+2 tiles) finishes early, leaving the big block ALONE at
// 1 wave/SIMD for most of its 32 tiles.
// Fix: order blocks by DESCENDING work (qt = 15 - rank). The HW dispatcher
// backfills CUs as slots free -> greedy LPT schedule: every CU keeps 2-3
// resident blocks (8-12 waves) until the endgame, makespan -> total/256 CUs
// (~34 tiles/CU). LDS 48 KB fits 3 blocks/CU (144<=160), VGPR 68 allows it.
// XCD-local bh bits (bid[4:0]) unchanged -> KV still L2-resident per XCD.
// Everything else identical to v4 (2 q-subtiles/wave, QBLK=128, max-free
// exp2 softmax, packed P, one barrier per tile).
// ---------------------------------------------------------------------------
__global__ __launch_bounds__(256, 2)
void attn_mfma(const short* __restrict__ qb, const short* __restrict__ kb,
               const short* __restrict__ vt, short* __restrict__ ao)
{
    __shared__ __align__(16) short Ks[2][64 * 64];
    __shared__ __align__(16) short Vs[2][64 * 64];   // [d][kv]
    __shared__ __align__(16) short Ps[8][16 * 64];   // per wave x 2 subs

    const int tid  = threadIdx.x;
    const int w    = tid >> 6;
    const int lane = tid & 63;
    const int m    = lane & 15;
    const int quad = lane >> 4;

    const int bid = blockIdx.x;
    const int bh  = ((bid & 7) << 2) | ((bid >> 3) & 3);   // bid[2:0]=xcd
    const int qt  = 15 - (bid >> 5);          // LPT: biggest blocks dispatch first
    const int b   = bh >> 4, h = bh & 15;

    int off8[8];
#pragma unroll
    for (int ks = 0; ks < 2; ks++)
#pragma unroll
        for (int nt = 0; nt < 4; nt++)
            off8[ks * 4 + nt] = (nt * 16 + m) * 64 + (((quad + 4 * ks) ^ (m & 7)) * 8);

    short* Ps0 = &Ps[w * 2 + 0][0];
    short* Ps1 = &Ps[w * 2 + 1][0];
    int pw[4], pr[2];
#pragma unroll
    for (int nt = 0; nt < 4; nt++)
        pw[nt] = m * 64 + (((2 * nt + (quad >> 1)) ^ (m & 7)) * 8) + (quad & 1) * 4;
#pragma unroll
    for (int ks = 0; ks < 2; ks++)
        pr[ks] = m * 64 + (((4 * ks + quad) ^ (m & 7)) * 8);

    const short* kbh = kb + (size_t)bh * T_ * HD_;
    const short* vbh = vt + (size_t)bh * HD_ * T_;

    // two 16-row q-subtiles per wave: rows qt*128 + w*32 + {0,16} + m
    const short* qp0 = qb + ((size_t)bh * T_ + qt * 128 + w * 32 + m) * HD_;
    const short* qp1 = qp0 + 16 * HD_;
    short8 qa0 = *(const short8*)(qp0 + quad * 8);
    short8 qa1 = *(const short8*)(qp0 + quad * 8 + 32);
    short8 qc0 = *(const short8*)(qp1 + quad * 8);
    short8 qc1 = *(const short8*)(qp1 + quad * 8 + 32);

    auto stage = [&](int kt2, int bi) {
        const int kbase = kt2 * 64;
#pragma unroll
        for (int it = 0; it < 2; it++) {
            int ci = it * 256 + tid;
            int rr = ci >> 3, cp = ci & 7, c = cp ^ (rr & 7);
            gld16(kbh + ((size_t)(kbase + rr)) * HD_ + c * 8, Ks[bi] + ci * 8);
            gld16(vbh + (size_t)rr * T_ + kbase + c * 8, Vs[bi] + ci * 8);
        }
    };

    const int NTL = 2 * qt + 2;   // kv tiles for this q-block (causal)

    stage(0, 0);
    __syncthreads();
    stage(1, 1);                  // NTL >= 2 always

    floatx4 o0[4], o1[4];
#pragma unroll
    for (int nt = 0; nt < 4; nt++) {
        o0[nt] = (floatx4){0.f, 0.f, 0.f, 0.f};
        o1[nt] = (floatx4){0.f, 0.f, 0.f, 0.f};
    }
    float lr0 = 0.f, lr1 = 0.f;

    for (int kt = 0; kt < NTL; kt++) {
        const int cur = kt & 1;
        const short* Kc = Ks[cur];
        const short* Vc = Vs[cur];

        // K fragments, shared by both q-subtiles
        short8 kf0[4], kf1[4];
#pragma unroll
        for (int nt = 0; nt < 4; nt++) {
            kf0[nt] = *(const short8*)(Kc + off8[nt]);
            kf1[nt] = *(const short8*)(Kc + off8[4 + nt]);
        }

        const int koff = (kt - 2 * qt) * 64;   // kv offset within diag region

        // S^T = K . Q^T (exp2 domain), softmax, packed-P store — per sub
        auto qk_sm = [&](short8 qA, short8 qB, short* PsS, int qloc, float& lr) {
            floatx4 s[4];
#pragma unroll
            for (int nt = 0; nt < 4; nt++) {
                floatx4 c = {0.f, 0.f, 0.f, 0.f};
                c = __builtin_amdgcn_mfma_f32_16x16x32_bf16(kf0[nt], qA, c, 0, 0, 0);
                c = __builtin_amdgcn_mfma_f32_16x16x32_bf16(kf1[nt], qB, c, 0, 0, 0);
                s[nt] = c;
            }
            if (kt >= 2 * qt) {                 // last two tiles: causal mask
#pragma unroll
                for (int nt = 0; nt < 4; nt++)
#pragma unroll
                    for (int rr = 0; rr < 4; rr++)
                        if (koff + nt * 16 + quad * 4 + rr > qloc) s[nt][rr] = -1e30f;
            }
            float rs = 0.f;
#pragma unroll
            for (int nt = 0; nt < 4; nt++) {
#pragma unroll
                for (int rr = 0; rr < 4; rr++) {
                    float p = fexp2(s[nt][rr]);   // bare v_exp_f32
                    rs += p;
                    s[nt][rr] = p;
                }
                uint2 pk;
                pk.x = pack2bf(s[nt][0], s[nt][1]);
                pk.y = pack2bf(s[nt][2], s[nt][3]);
                *(uint2*)(PsS + pw[nt]) = pk;
            }
            rs += __shfl_xor(rs, 16, 64);
            rs += __shfl_xor(rs, 32, 64);
            lr += rs;
        };
        qk_sm(qa0, qa1, Ps0, w * 32 + m,      lr0);
        qk_sm(qc0, qc1, Ps1, w * 32 + 16 + m, lr1);

        short8 p00 = *(const short8*)(Ps0 + pr[0]);
        short8 p01 = *(const short8*)(Ps0 + pr[1]);
        short8 p10 = *(const short8*)(Ps1 + pr[0]);
        short8 p11 = *(const short8*)(Ps1 + pr[1]);

#pragma unroll
        for (int nt = 0; nt < 4; nt++) {
            short8 v0 = *(const short8*)(Vc + off8[nt]);
            short8 v1 = *(const short8*)(Vc + off8[4 + nt]);
            o0[nt] = __builtin_amdgcn_mfma_f32_16x16x32_bf16(v0, p00, o0[nt], 0, 0, 0);
            o0[nt] = __builtin_amdgcn_mfma_f32_16x16x32_bf16(v1, p01, o0[nt], 0, 0, 0);
            o1[nt] = __builtin_amdgcn_mfma_f32_16x16x32_bf16(v0, p10, o1[nt], 0, 0, 0);
            o1[nt] = __builtin_amdgcn_mfma_f32_16x16x32_bf16(v1, p11, o1[nt], 0, 0, 0);
        }

        __syncthreads();
        if (kt + 2 < NTL) stage(kt + 2, cur);
    }

    const float inv0 = 1.0f / lr0;
    const float inv1 = 1.0f / lr1;
    const int q0 = qt * 128 + w * 32 + m;
    short* dst0 = ao + ((size_t)b * T_ + q0) * C_ + h * HD_;
    short* dst1 = dst0 + 16 * C_;
#pragma unroll
    for (int nt = 0; nt < 4; nt++) {
        ushort4 u;
        u.x = (unsigned short)f2bf(o0[nt][0] * inv0);
        u.y = (unsigned short)f2bf(o0[nt][1] * inv0);
        u.z = (unsigned short)f2bf(o0[nt][2] * inv0);
        u.w = (unsigned short)f2bf(o0[nt][3] * inv0);
        *(ushort4*)(dst0 + nt * 16 + quad * 4) = u;
        ushort4 u2;
        u2.x = (unsigned short)f2bf(o1[nt][0] * inv1);
        u2.y = (unsigned short)f2bf(o1[nt][1] * inv1);
        u2.z = (unsigned short)f2bf(o1[nt][2] * inv1);
        u2.w = (unsigned short)f2bf(o1[nt][3] * inv1);
        *(ushort4*)(dst1 + nt * 16 + quad * 4) = u2;
    }
}

// ---------------------------------------------------------------------------
extern "C" void kernel_launch(void* const* d_in, const int* in_sizes, int n_in,
                              void* d_out, int out_size, void* d_ws, size_t ws_size,
                              hipStream_t stream)
{
    const float* x     = (const float*)d_in[0];
    const float* qkv_w = (const float*)d_in[2];
    const float* qkv_b = (const float*)d_in[3];
    const float* out_w = (const float*)d_in[4];
    const float* out_b = (const float*)d_in[5];
    float* out = (float*)d_out;

    const size_t BTC = (size_t)B_ * T_ * C_;     // 4,194,304
    short* xb  = (short*)d_ws;                   // [B,T,C]    bf16
    short* w1b = xb  + BTC;                      // [3C,C]     bf16
    short* w2b = w1b + 3 * (size_t)C_ * C_;      // [C,C]      bf16
    short* qbw = w2b + (size_t)C_ * C_;          // [B,H,T,HD] bf16 (x0.125*log2e)
    short* kbw = qbw + BTC;                      // [B,H,T,HD] bf16
    short* vtw = kbw + BTC;                      // [B,H,HD,T] bf16
    short* aob = vtw + BTC;                      // [B,T,C]    bf16

    // 0) casts
    cast3<<<4096, 256, 0, stream>>>(x, qkv_w, out_w, xb, w1b, w2b);

    // 1) QKV projection: 128x64x64 (nk=16), scatter epilogue
    dim3 g1(3 * C_ / 64, B_ * T_ / 128);         // (48, 32) = 1536 blocks
    gemm_bf16<1, 128, 64, 64><<<g1, 256, 0, stream>>>(xb, w1b, qkv_b, nullptr,
                                                      qbw, kbw, vtw,
                                                      B_ * T_, 3 * C_, C_);

    // 2) causal attention v5: QBLK=128, LPT descending-qt map, 512 blocks
    attn_mfma<<<512, 256, 0, stream>>>(qbw, kbw, vtw, aob);

    // 3) output projection: 128x64x64 (QKV-proven shape, 512 blocks) -> d_out
    dim3 g3(C_ / 64, B_ * T_ / 128);             // (16, 32) = 512 blocks
    gemm_bf16<0, 128, 64, 64><<<g3, 256, 0, stream>>>(aob, w2b, out_b, out,
                                                      nullptr, nullptr, nullptr,
                                                      B_ * T_, C_, C_);
}

// Round 4
// 185.360 us; speedup vs baseline: 1.0164x; 1.0164x over previous
//
#include <hip/hip_runtime.h>
#include <hip/hip_bf16.h>
#include <math.h>

#define B_  2
#define T_  2048
#define C_  1024
#define H_  16
#define HD_ 64

typedef __attribute__((ext_vector_type(8))) short short8;
typedef __attribute__((ext_vector_type(4))) float floatx4;

__device__ __forceinline__ short f2bf(float f) {
    __hip_bfloat16 h = __float2bfloat16(f);
    return *reinterpret_cast<short*>(&h);
}

// fast 2^x (v_exp_f32 IS exp2)
__device__ __forceinline__ float fexp2(float x) {
#if __has_builtin(__builtin_amdgcn_exp2f)
    return __builtin_amdgcn_exp2f(x);
#else
    return exp2f(x);
#endif
}

// pack two fp32 -> two bf16 (truncating) in ONE v_perm_b32
__device__ __forceinline__ unsigned pack2bf(float a, float b) {
    return __builtin_amdgcn_perm(__float_as_uint(b), __float_as_uint(a),
                                 0x07060302u);
}

__device__ __forceinline__ void gld16(const void* g, void* l) {
    __builtin_amdgcn_global_load_lds(
        (const __attribute__((address_space(1))) void*)g,
        (__attribute__((address_space(3))) void*)l, 16, 0, 0);
}

// ---------------------------------------------------------------------------
// Cast x, qkv_w, out_w to bf16 (one shot, memory-bound).
// R14 lesson: the standalone cast is CHEAPER than fusing conversion into the
// GEMMs (fused fp32 staging re-reads operands in fp32 per block: FETCH x2.3).
// ---------------------------------------------------------------------------
__global__ __launch_bounds__(256)
void cast3(const float* __restrict__ x, const float* __restrict__ w1,
           const float* __restrict__ w2, short* __restrict__ xo,
           short* __restrict__ w1o, short* __restrict__ w2o)
{
    int gid = blockIdx.x * 256 + threadIdx.x;       // 1,048,576 threads x 8 elems
    const float* s; short* d; int off;
    if (gid < 524288)      { s = x;  d = xo;  off = gid; }
    else if (gid < 917504) { s = w1; d = w1o; off = gid - 524288; }
    else                   { s = w2; d = w2o; off = gid - 917504; }
    float4 a = ((const float4*)s)[(size_t)off * 2];
    float4 b = ((const float4*)s)[(size_t)off * 2 + 1];
    short8 v;
    v[0] = f2bf(a.x); v[1] = f2bf(a.y); v[2] = f2bf(a.z); v[3] = f2bf(a.w);
    v[4] = f2bf(b.x); v[5] = f2bf(b.y); v[6] = f2bf(b.z); v[7] = f2bf(b.w);
    *(short8*)(d + (size_t)off * 8) = v;
}

// ---------------------------------------------------------------------------
// bf16 MFMA GEMM (NT): out = A @ W^T + bias.  A:[M,K] bf16, W:[N,K] bf16.
// BM x BN x BK tile, 256 threads (4 waves 2x2). nk = K/BK steps; BK=64 sweet
// spot (R7-R12). Double-buffered LDS, one __syncthreads per step, distance-1
// prefetch; XOR chunk swizzle.
// MODE 0: fp32 out[m*N+n] + bias
// MODE 1: QKV scatter -> qb [B,H,T,HD] (x0.125*log2e), kb, vt [B,H,HD,T]
// ---------------------------------------------------------------------------
template<int MODE, int BM, int BN, int BK>
__global__ __launch_bounds__(256, 4)
void gemm_bf16(const short* __restrict__ A, const short* __restrict__ W,
               const float* __restrict__ bias, float* __restrict__ out,
               short* __restrict__ qb, short* __restrict__ kb,
               short* __restrict__ vt, int M, int N, int K)
{
    constexpr int MI  = BM / 32;
    constexpr int NJ  = BN / 32;
    constexpr int KS  = BK / 32;
    constexpr int CPR = BK / 8;
    constexpr int LC  = (CPR == 8) ? 3 : 4;
    constexpr int RPT = 256 / CPR;
    __shared__ __align__(16) short As[2][BM * BK];
    __shared__ __align__(16) short Bs[2][BN * BK];

    const int tid  = threadIdx.x;
    const int lane = tid & 63;
    const int w    = tid >> 6;
    const int m    = lane & 15, quad = lane >> 4;
    const int wrow = w >> 1, wcol = w & 1;
    const int nb = blockIdx.x, mb = blockIdx.y;

    const int g = (tid & (CPR - 1)) ^ ((tid >> LC) & (CPR - 1));
    const short* Ag = A + (size_t)(mb * BM + (tid >> LC)) * K + g * 8;
    const short* Wg = W + (size_t)(nb * BN + (tid >> LC)) * K + g * 8;

    int aoff[MI][KS], boff[NJ][KS];
#pragma unroll
    for (int i = 0; i < MI; i++) {
        int ar = wrow * (BM / 2) + i * 16 + m;
#pragma unroll
        for (int ks = 0; ks < KS; ks++)
            aoff[i][ks] = ar * BK + (((ks * 4 + quad) ^ (ar & (CPR - 1))) * 8);
    }
#pragma unroll
    for (int j = 0; j < NJ; j++) {
        int bc = wcol * (BN / 2) + j * 16 + m;
#pragma unroll
        for (int ks = 0; ks < KS; ks++)
            boff[j][ks] = bc * BK + (((ks * 4 + quad) ^ (bc & (CPR - 1))) * 8);
    }

    floatx4 acc[MI][NJ];
#pragma unroll
    for (int i = 0; i < MI; i++)
#pragma unroll
        for (int j = 0; j < NJ; j++) acc[i][j] = (floatx4){0.f, 0.f, 0.f, 0.f};

    auto stage = [&](int k0, int bi) {
#pragma unroll
        for (int i = 0; i < BM / RPT; i++)
            gld16(Ag + (size_t)(i * RPT) * K + k0, As[bi] + i * 2048 + tid * 8);
#pragma unroll
        for (int i = 0; i < BN / RPT; i++)
            gld16(Wg + (size_t)(i * RPT) * K + k0, Bs[bi] + i * 2048 + tid * 8);
    };

    const int nk = K / BK;
    stage(0, 0);
    __syncthreads();

    for (int ki = 0; ki < nk; ki++) {
        const int cur = ki & 1;
        if (ki + 1 < nk) stage((ki + 1) * BK, cur ^ 1);

        const short* Ac = &As[cur][0];
        const short* Bc = &Bs[cur][0];
        short8 af[MI][KS], bfr[NJ][KS];
#pragma unroll
        for (int i = 0; i < MI; i++)
#pragma unroll
            for (int ks = 0; ks < KS; ks++)
                af[i][ks] = *(const short8*)(Ac + aoff[i][ks]);
#pragma unroll
        for (int j = 0; j < NJ; j++)
#pragma unroll
            for (int ks = 0; ks < KS; ks++)
                bfr[j][ks] = *(const short8*)(Bc + boff[j][ks]);
#pragma unroll
        for (int i = 0; i < MI; i++)
#pragma unroll
            for (int j = 0; j < NJ; j++)
#pragma unroll
                for (int ks = 0; ks < KS; ks++)
                    acc[i][j] = __builtin_amdgcn_mfma_f32_16x16x32_bf16(
                        af[i][ks], bfr[j][ks], acc[i][j], 0, 0, 0);
        __syncthreads();
    }

    // C/D layout: col(n) = lane&15, row(m) = quad*4 + reg  [m89/m91 verified]
    const int row0 = mb * BM + wrow * (BM / 2);
    const int col0 = nb * BN + wcol * (BN / 2);

    if (MODE == 0) {
#pragma unroll
        for (int j = 0; j < NJ; j++) {
            int n = col0 + j * 16 + m;
            float bn = bias[n];
#pragma unroll
            for (int i = 0; i < MI; i++) {
#pragma unroll
                for (int r = 0; r < 4; r++) {
                    int mm = row0 + i * 16 + quad * 4 + r;
                    out[(size_t)mm * N + n] = acc[i][j][r] + bn;
                }
            }
        }
    } else {
        const int sec = col0 >> 10;               // 0=q 1=k 2=v
        const int h   = (col0 >> 6) & 15;
        if (sec <= 1) {
            short* dst = sec ? kb : qb;
            // q scale folds 1/sqrt(64) AND log2(e): softmax runs in exp2 domain
            const float sc = sec ? 1.0f : 0.18033688011112042f;
#pragma unroll
            for (int j = 0; j < NJ; j++) {
                int n = col0 + j * 16 + m;
                int d = n & 63;
                float bn = bias[n];
#pragma unroll
                for (int i = 0; i < MI; i++) {
                    int t0 = row0 + i * 16 + quad * 4;
                    int b  = t0 >> 11;
                    int t  = t0 & (T_ - 1);
#pragma unroll
                    for (int r = 0; r < 4; r++)
                        dst[((size_t)(b * H_ + h) * T_ + t + r) * HD_ + d] =
                            f2bf((acc[i][j][r] + bn) * sc);
                }
            }
        } else {
#pragma unroll
            for (int j = 0; j < NJ; j++) {
                int n = col0 + j * 16 + m;
                int d = n & 63;
                float bn = bias[n];
#pragma unroll
                for (int i = 0; i < MI; i++) {
                    int t0 = row0 + i * 16 + quad * 4;
                    int b  = t0 >> 11;
                    int t  = t0 & (T_ - 1);
                    ushort4 u;
                    u.x = (unsigned short)f2bf(acc[i][j][0] + bn);
                    u.y = (unsigned short)f2bf(acc[i][j][1] + bn);
                    u.z = (unsigned short)f2bf(acc[i][j][2] + bn);
                    u.w = (unsigned short)f2bf(acc[i][j][3] + bn);
                    *(ushort4*)(vt + ((size_t)(b * H_ + h) * HD_ + d) * T_ + t) = u;
                }
            }
        }
    }
}

// ---------------------------------------------------------------------------
// bf16 MFMA causal flash attention v6 — R18: uniform-work pair blocks.
// R16/R17 lesson: 512 blocks x 48KB = the WHOLE grid is co-resident (2/CU),
// so dispatch order is irrelevant (LPT was neutral) and per-block work
// heterogeneity (2..32 tiles) becomes intra-CU tail idle: the small partner
// finishes, the big block runs alone at 1 wave/SIMD. Occupancy 11.7% both maps.
// v6: one block owns the q-tile PAIR (qA=31-p, qB=p) of one bh at QBLK=64,
// 16 rows/wave. B's KV range [0,qB] is a SUBSET of A's [0,qA], so B's
// sub-tiles are computed against the SAME staged KV while streaming A:
// per-tile K/V fragments feed both q-subtiles (v4's reuse), and every block
// computes EXACTLY (qA+1)+(qB+1) = 33 sub-tile units -> constant 8 waves/CU,
// zero tail. `kt <= qB` is block-uniform (no divergence). Staging rises to
// qA+1 tiles/block (17..32) but KV is L2-resident per XCD (HBM at 3.6%).
// Max-free exp2 softmax, packed P, one barrier per tile. LDS 48KB, VGPR ~72.
// ---------------------------------------------------------------------------
__global__ __launch_bounds__(256, 2)
void attn_mfma(const short* __restrict__ qb, const short* __restrict__ kb,
               const short* __restrict__ vt, short* __restrict__ ao)
{
    __shared__ __align__(16) short Ks[2][64 * 64];
    __shared__ __align__(16) short Vs[2][64 * 64];   // [d][kv]
    __shared__ __align__(16) short Ps[8][16 * 64];   // per wave x 2 subs

    const int tid  = threadIdx.x;
    const int w    = tid >> 6;
    const int lane = tid & 63;
    const int m    = lane & 15;
    const int quad = lane >> 4;

    const int bid = blockIdx.x;
    const int bh  = ((bid & 7) << 2) | ((bid >> 3) & 3);   // bid[2:0]=xcd
    const int p   = (bid >> 5) & 15;          // pair index
    const int qA  = 31 - p;                   // big q-tile (17..32 kv tiles)
    const int qB  = p;                        // small q-tile (1..16 kv tiles)
    const int b   = bh >> 4, h = bh & 15;

    int off8[8];
#pragma unroll
    for (int ks = 0; ks < 2; ks++)
#pragma unroll
        for (int nt = 0; nt < 4; nt++)
            off8[ks * 4 + nt] = (nt * 16 + m) * 64 + (((quad + 4 * ks) ^ (m & 7)) * 8);

    short* Ps0 = &Ps[w * 2 + 0][0];
    short* Ps1 = &Ps[w * 2 + 1][0];
    int pw[4], pr[2];
#pragma unroll
    for (int nt = 0; nt < 4; nt++)
        pw[nt] = m * 64 + (((2 * nt + (quad >> 1)) ^ (m & 7)) * 8) + (quad & 1) * 4;
#pragma unroll
    for (int ks = 0; ks < 2; ks++)
        pr[ks] = m * 64 + (((4 * ks + quad) ^ (m & 7)) * 8);

    const short* kbh = kb + (size_t)bh * T_ * HD_;
    const short* vbh = vt + (size_t)bh * HD_ * T_;

    // q rows: sub A = qA*64 + w*16 + m, sub B = qB*64 + w*16 + m
    const short* qpA = qb + ((size_t)bh * T_ + qA * 64 + w * 16 + m) * HD_;
    const short* qpB = qb + ((size_t)bh * T_ + qB * 64 + w * 16 + m) * HD_;
    short8 qa0 = *(const short8*)(qpA + quad * 8);
    short8 qa1 = *(const short8*)(qpA + quad * 8 + 32);
    short8 qc0 = *(const short8*)(qpB + quad * 8);
    short8 qc1 = *(const short8*)(qpB + quad * 8 + 32);

    auto stage = [&](int kt2, int bi) {
        const int kbase = kt2 * 64;
#pragma unroll
        for (int it = 0; it < 2; it++) {
            int ci = it * 256 + tid;
            int rr = ci >> 3, cp = ci & 7, c = cp ^ (rr & 7);
            gld16(kbh + ((size_t)(kbase + rr)) * HD_ + c * 8, Ks[bi] + ci * 8);
            gld16(vbh + (size_t)rr * T_ + kbase + c * 8, Vs[bi] + ci * 8);
        }
    };

    const int NTL = qA + 1;       // staged kv tiles (>= 17)

    stage(0, 0);
    __syncthreads();
    stage(1, 1);

    floatx4 o0[4], o1[4];
#pragma unroll
    for (int nt = 0; nt < 4; nt++) {
        o0[nt] = (floatx4){0.f, 0.f, 0.f, 0.f};
        o1[nt] = (floatx4){0.f, 0.f, 0.f, 0.f};
    }
    float lr0 = 0.f, lr1 = 0.f;

    for (int kt = 0; kt < NTL; kt++) {
        const int cur = kt & 1;
        const short* Kc = Ks[cur];
        const short* Vc = Vs[cur];
        const bool doB = (kt <= qB);          // block-uniform branch

        // K fragments, shared by both q-subtiles
        short8 kf0[4], kf1[4];
#pragma unroll
        for (int nt = 0; nt < 4; nt++) {
            kf0[nt] = *(const short8*)(Kc + off8[nt]);
            kf1[nt] = *(const short8*)(Kc + off8[4 + nt]);
        }

        // S^T = K . Q^T (exp2 domain), softmax, packed-P store — per sub.
        // diag: mask kv pos (within tile) > q pos (within 64-row subtile).
        auto qk_sm = [&](short8 qX, short8 qY, short* PsS, bool diag, float& lr) {
            floatx4 s[4];
#pragma unroll
            for (int nt = 0; nt < 4; nt++) {
                floatx4 c = {0.f, 0.f, 0.f, 0.f};
                c = __builtin_amdgcn_mfma_f32_16x16x32_bf16(kf0[nt], qX, c, 0, 0, 0);
                c = __builtin_amdgcn_mfma_f32_16x16x32_bf16(kf1[nt], qY, c, 0, 0, 0);
                s[nt] = c;
            }
            if (diag) {
#pragma unroll
                for (int nt = 0; nt < 4; nt++)
#pragma unroll
                    for (int rr = 0; rr < 4; rr++)
                        if (nt * 16 + quad * 4 + rr > w * 16 + m) s[nt][rr] = -1e30f;
            }
            float rs = 0.f;
#pragma unroll
            for (int nt = 0; nt < 4; nt++) {
#pragma unroll
                for (int rr = 0; rr < 4; rr++) {
                    float pv = fexp2(s[nt][rr]);   // bare v_exp_f32
                    rs += pv;
                    s[nt][rr] = pv;
                }
                uint2 pk;
                pk.x = pack2bf(s[nt][0], s[nt][1]);
                pk.y = pack2bf(s[nt][2], s[nt][3]);
                *(uint2*)(PsS + pw[nt]) = pk;
            }
            rs += __shfl_xor(rs, 16, 64);
            rs += __shfl_xor(rs, 32, 64);
            lr += rs;
        };
        qk_sm(qa0, qa1, Ps0, kt == qA, lr0);
        if (doB) qk_sm(qc0, qc1, Ps1, kt == qB, lr1);

        short8 p00 = *(const short8*)(Ps0 + pr[0]);
        short8 p01 = *(const short8*)(Ps0 + pr[1]);

#pragma unroll
        for (int nt = 0; nt < 4; nt++) {
            short8 v0 = *(const short8*)(Vc + off8[nt]);
            short8 v1 = *(const short8*)(Vc + off8[4 + nt]);
            o0[nt] = __builtin_amdgcn_mfma_f32_16x16x32_bf16(v0, p00, o0[nt], 0, 0, 0);
            o0[nt] = __builtin_amdgcn_mfma_f32_16x16x32_bf16(v1, p01, o0[nt], 0, 0, 0);
        }
        if (doB) {
            short8 p10 = *(const short8*)(Ps1 + pr[0]);
            short8 p11 = *(const short8*)(Ps1 + pr[1]);
#pragma unroll
            for (int nt = 0; nt < 4; nt++) {
                short8 v0 = *(const short8*)(Vc + off8[nt]);
                short8 v1 = *(const short8*)(Vc + off8[4 + nt]);
                o1[nt] = __builtin_amdgcn_mfma_f32_16x16x32_bf16(v0, p10, o1[nt], 0, 0, 0);
                o1[nt] = __builtin_amdgcn_mfma_f32_16x16x32_bf16(v1, p11, o1[nt], 0, 0, 0);
            }
        }

        __syncthreads();
        if (kt + 2 < NTL) stage(kt + 2, cur);
    }

    const float inv0 = 1.0f / lr0;
    const float inv1 = 1.0f / lr1;
    const int rA = qA * 64 + w * 16 + m;
    const int rB = qB * 64 + w * 16 + m;
    short* dst0 = ao + ((size_t)b * T_ + rA) * C_ + h * HD_;
    short* dst1 = ao + ((size_t)b * T_ + rB) * C_ + h * HD_;
#pragma unroll
    for (int nt = 0; nt < 4; nt++) {
        ushort4 u;
        u.x = (unsigned short)f2bf(o0[nt][0] * inv0);
        u.y = (unsigned short)f2bf(o0[nt][1] * inv0);
        u.z = (unsigned short)f2bf(o0[nt][2] * inv0);
        u.w = (unsigned short)f2bf(o0[nt][3] * inv0);
        *(ushort4*)(dst0 + nt * 16 + quad * 4) = u;
        ushort4 u2;
        u2.x = (unsigned short)f2bf(o1[nt][0] * inv1);
        u2.y = (unsigned short)f2bf(o1[nt][1] * inv1);
        u2.z = (unsigned short)f2bf(o1[nt][2] * inv1);
        u2.w = (unsigned short)f2bf(o1[nt][3] * inv1);
        *(ushort4*)(dst1 + nt * 16 + quad * 4) = u2;
    }
}

// ---------------------------------------------------------------------------
extern "C" void kernel_launch(void* const* d_in, const int* in_sizes, int n_in,
                              void* d_out, int out_size, void* d_ws, size_t ws_size,
                              hipStream_t stream)
{
    const float* x     = (const float*)d_in[0];
    const float* qkv_w = (const float*)d_in[2];
    const float* qkv_b = (const float*)d_in[3];
    const float* out_w = (const float*)d_in[4];
    const float* out_b = (const float*)d_in[5];
    float* out = (float*)d_out;

    const size_t BTC = (size_t)B_ * T_ * C_;     // 4,194,304
    short* xb  = (short*)d_ws;                   // [B,T,C]    bf16
    short* w1b = xb  + BTC;                      // [3C,C]     bf16
    short* w2b = w1b + 3 * (size_t)C_ * C_;      // [C,C]      bf16
    short* qbw = w2b + (size_t)C_ * C_;          // [B,H,T,HD] bf16 (x0.125*log2e)
    short* kbw = qbw + BTC;                      // [B,H,T,HD] bf16
    short* vtw = kbw + BTC;                      // [B,H,HD,T] bf16
    short* aob = vtw + BTC;                      // [B,T,C]    bf16

    // 0) casts
    cast3<<<4096, 256, 0, stream>>>(x, qkv_w, out_w, xb, w1b, w2b);

    // 1) QKV projection: 128x64x64 (nk=16), scatter epilogue
    dim3 g1(3 * C_ / 64, B_ * T_ / 128);         // (48, 32) = 1536 blocks
    gemm_bf16<1, 128, 64, 64><<<g1, 256, 0, stream>>>(xb, w1b, qkv_b, nullptr,
                                                      qbw, kbw, vtw,
                                                      B_ * T_, 3 * C_, C_);

    // 2) causal attention v6: uniform-work pair blocks, 512 blocks
    attn_mfma<<<512, 256, 0, stream>>>(qbw, kbw, vtw, aob);

    // 3) output projection: 128x64x64 (QKV-proven shape, 512 blocks) -> d_out
    dim3 g3(C_ / 64, B_ * T_ / 128);             // (16, 32) = 512 blocks
    gemm_bf16<0, 128, 64, 64><<<g3, 256, 0, stream>>>(aob, w2b, out_b, out,
                                                      nullptr, nullptr, nullptr,
                                                      B_ * T_, C_, C_);
}